// Round 14
// baseline (232.357 us; speedup 1.0000x reference)
//
#include <hip/hip_runtime.h>
#include <hip/hip_bf16.h>

using bf16 = __hip_bfloat16;
typedef __attribute__((ext_vector_type(8))) short short8;
typedef __attribute__((ext_vector_type(4))) float f32x4;

static constexpr int Bc = 4, Lc = 2048, Sc = 1024;
static constexpr int DModel = 1024;

__device__ __forceinline__ void gload16(const void* g, void* l) {
  __builtin_amdgcn_global_load_lds((const __attribute__((address_space(1))) void*)g,
                                   (__attribute__((address_space(3))) void*)l,
                                   16, 0, 0);
}

__device__ __forceinline__ void wait_vm8()  { asm volatile("s_waitcnt vmcnt(8)" ::: "memory"); }
__device__ __forceinline__ void wait_vm6()  { asm volatile("s_waitcnt vmcnt(6)" ::: "memory"); }
__device__ __forceinline__ void wait_vm3()  { asm volatile("s_waitcnt vmcnt(3)" ::: "memory"); }
__device__ __forceinline__ void wait_vm2()  { asm volatile("s_waitcnt vmcnt(2)" ::: "memory"); }
__device__ __forceinline__ void wait_vm0()  { asm volatile("s_waitcnt vmcnt(0)" ::: "memory"); }
__device__ __forceinline__ void barrier_raw() { asm volatile("s_barrier" ::: "memory"); }

// ---------------- prep: weight transposes + activation conversions, ONE launch --
__global__ __launch_bounds__(256) void prep(
    const float* __restrict__ Wq, bf16* __restrict__ WqT,
    const float* __restrict__ Wk, bf16* __restrict__ WkT,
    const float* __restrict__ Wv, bf16* __restrict__ WvT,
    const float* __restrict__ Wo, bf16* __restrict__ WoT,
    const float* __restrict__ a, bf16* __restrict__ ao, long na4,
    const float* __restrict__ b, bf16* __restrict__ bo, long nb4,
    const float* __restrict__ c, bf16* __restrict__ co, long nc4) {
  __shared__ bf16 tile[32][33];
  int bid = blockIdx.x;
  if (bid < 10240) {
    const float* in; bf16* out; int R, l;
    if (bid < 1024)      { in = Wq; out = WqT; R = 1024; l = bid; }
    else if (bid < 5120) { in = Wk; out = WkT; R = 4096; l = bid - 1024; }
    else if (bid < 9216) { in = Wv; out = WvT; R = 4096; l = bid - 5120; }
    else                 { in = Wo; out = WoT; R = 1024; l = bid - 9216; }
    const int C = 1024;
    int bx = l & 31, by = l >> 5;
    int tx = threadIdx.x & 31, ty = threadIdx.x >> 5;
    int r0 = by * 32, c0 = bx * 32;
#pragma unroll
    for (int i = 0; i < 32; i += 8)
      tile[ty + i][tx] = __float2bfloat16(in[(long)(r0 + ty + i) * C + c0 + tx]);
    __syncthreads();
#pragma unroll
    for (int i = 0; i < 32; i += 8)
      out[(long)(c0 + ty + i) * R + r0 + tx] = tile[tx][ty + i];
  } else {
    int cb = bid - 10240;
    long total = na4 + nb4 + nc4;
    long stride = (long)(gridDim.x - 10240) * blockDim.x;
    for (long i = (long)cb * blockDim.x + threadIdx.x; i < total; i += stride) {
      const float* src; bf16* dst; long j;
      if (i < na4)            { src = a; dst = ao; j = i; }
      else if (i < na4 + nb4) { src = b; dst = bo; j = i - na4; }
      else                    { src = c; dst = co; j = i - na4 - nb4; }
      float4 v = reinterpret_cast<const float4*>(src)[j];
      alignas(8) bf16 t[4] = {__float2bfloat16(v.x), __float2bfloat16(v.y),
                              __float2bfloat16(v.z), __float2bfloat16(v.w)};
      reinterpret_cast<ushort4*>(dst)[j] = *reinterpret_cast<const ushort4*>(t);
    }
  }
}

// ======== balanced QKV GEMM: 256x128 tile, BK=32, 8 waves, 3-deep LDS ========
// (R8/R12's proven bf16 core: 110 us, MfmaUtil 34%, no spill.)
__device__ __forceinline__ void gemm_bal_core(const bf16* __restrict__ A, const bf16* __restrict__ Bt,
                                              const float* __restrict__ bias,
                                              bf16* __restrict__ Cb, bf16* __restrict__ Cvt,
                                              int K, int bx, int by, bf16* lds) {
  const int tid = threadIdx.x;
  const int lane = tid & 63, g = lane >> 4, lm = lane & 15;
  const int wid = tid >> 6, wr = wid >> 1, wc = wid & 1;  // 4M x 2N waves, 64x64 each
  const long brow = (long)by * 256, bcol = (long)bx * 128;

  char* L = (char*)lds;
  const int rowA = tid >> 2;
  const int kg = (tid & 3) ^ ((rowA >> 1) & 3);  // source pre-swizzle
  const bf16* aS = A + (brow + rowA) * (long)K + kg * 8;
  const bf16* bS = Bt + (bcol + rowA) * (long)K + kg * 8;
  const long aOff1 = 128l * K;
  const int dA = tid * 16;

#define STAGEB(t_) {                                                     \
    const int _b = (t_) % 3; const long _ko = (long)(t_) * 32;           \
    gload16(aS + _ko,         L + _b * 24576 + dA);                      \
    gload16(aS + aOff1 + _ko, L + _b * 24576 + 8192 + dA);               \
    gload16(bS + _ko,         L + _b * 24576 + 16384 + dA); }

  f32x4 zero = {0.f, 0.f, 0.f, 0.f};
  f32x4 acc[4][4];
#pragma unroll
  for (int i = 0; i < 4; ++i)
#pragma unroll
    for (int j = 0; j < 4; ++j) acc[i][j] = zero;

  STAGEB(0);
  STAGEB(1);

  const int nt = K >> 5;
  for (int t = 0; t < nt; ++t) {
    if (t + 2 < nt)       { STAGEB(t + 2); wait_vm6(); }  // certify tile t
    else if (t + 2 == nt) wait_vm3();
    else                  wait_vm0();
    barrier_raw();

    const char* Bf = L + (t % 3) * 24576;
    short8 aR[4], bR[4];
#pragma unroll
    for (int mi = 0; mi < 4; ++mi) {
      const int r = wr * 64 + mi * 16 + lm;
      aR[mi] = *reinterpret_cast<const short8*>(
          Bf + r * 64 + ((g ^ ((r >> 1) & 3)) << 4));
    }
#pragma unroll
    for (int ni = 0; ni < 4; ++ni) {
      const int r = wc * 64 + ni * 16 + lm;
      bR[ni] = *reinterpret_cast<const short8*>(
          Bf + 16384 + r * 64 + ((g ^ ((r >> 1) & 3)) << 4));
    }
    __builtin_amdgcn_s_setprio(1);
#pragma unroll
    for (int mi = 0; mi < 4; ++mi)
#pragma unroll
      for (int ni = 0; ni < 4; ++ni)
        acc[mi][ni] = __builtin_amdgcn_mfma_f32_16x16x32_bf16(aR[mi], bR[ni], acc[mi][ni], 0, 0, 0);
    __builtin_amdgcn_s_setprio(0);
    barrier_raw();
  }
#undef STAGEB

#pragma unroll
  for (int ni = 0; ni < 4; ++ni) {
    long n = bcol + wc * 64 + ni * 16 + lm;
    float bv = bias ? bias[n] : 0.f;
#pragma unroll
    for (int mi = 0; mi < 4; ++mi) {
      long m0 = brow + wr * 64 + mi * 16 + g * 4;
      if (Cvt) {  // V-proj: write vT [b][n][s]
        long b = m0 >> 10, s0 = m0 & 1023;
        alignas(8) bf16 t4[4];
#pragma unroll
        for (int r = 0; r < 4; ++r) t4[r] = __float2bfloat16(acc[mi][ni][r] + bv);
        *reinterpret_cast<ushort4*>(Cvt + ((b << 10) + n) * 1024 + s0) =
            *reinterpret_cast<const ushort4*>(t4);
      } else {
#pragma unroll
        for (int r = 0; r < 4; ++r)
          Cb[(m0 + r) * 1024 + n] = __float2bfloat16(acc[mi][ni][r] + bv);
      }
    }
  }
}

// QKV fused, balanced: K 128 blocks (nt=128), V 128 (nt=128), Q 256 (nt=32).
__global__ __launch_bounds__(512, 4) void gemm_qkv_bal(
    const bf16* __restrict__ Ak, const bf16* __restrict__ Bk, const float* __restrict__ bk_, bf16* __restrict__ Ck, int Kk, int nbk,
    const bf16* __restrict__ Av, const bf16* __restrict__ Bv_, const float* __restrict__ bv_, bf16* __restrict__ CvT, int Kv, int nbv,
    const bf16* __restrict__ Aq, const bf16* __restrict__ Bq_, const float* __restrict__ bq_, bf16* __restrict__ Cq, int Kq) {
  __shared__ bf16 lds[36864];  // 72 KB
  int bid = blockIdx.x;
  const bf16 *A, *Bt; const float* bias; bf16 *C = nullptr, *Cvt = nullptr; int K, l, nb;
  if (bid < nbk)            { A = Ak; Bt = Bk;  bias = bk_; C = Ck;    K = Kk; l = bid;             nb = nbk; }
  else if (bid < nbk + nbv) { A = Av; Bt = Bv_; bias = bv_; Cvt = CvT; K = Kv; l = bid - nbk;       nb = nbv; }
  else                      { A = Aq; Bt = Bq_; bias = bq_; C = Cq;   K = Kq; l = bid - nbk - nbv; nb = gridDim.x - nbk - nbv; }
  int g = (l & 7) * (nb >> 3) + (l >> 3);
  gemm_bal_core(A, Bt, bias, C, Cvt, K, g & 7, g >> 3, lds);
}

// ---------------- 128^2 GEMM (2-phase dbuf, counted vmcnt) for O-proj ----------
__device__ __forceinline__ void gemm_core(const bf16* __restrict__ A, const bf16* __restrict__ Bt,
                                          const float* __restrict__ bias,
                                          bf16* __restrict__ Cb, float* __restrict__ Cf,
                                          int N, int K, int bx, int by,
                                          bf16* As, bf16* Bs) {
  const int tid = threadIdx.x;
  const int lane = tid & 63, g = lane >> 4, lm = lane & 15;
  const int wid = tid >> 6, wr = wid >> 1, wc = wid & 1;
  const long brow = (long)by * 128, bcol = (long)bx * 128;

  const bf16* asrc[4];
  const bf16* bsrc[4];
  int dsto[4];
#pragma unroll
  for (int t = 0; t < 4; ++t) {
    int sl = tid + t * 256;
    int row = sl >> 3;
    int kg = (sl & 7) ^ (row & 7);
    asrc[t] = A + (brow + row) * (long)K + kg * 8;
    bsrc[t] = Bt + (bcol + row) * (long)K + kg * 8;
    dsto[t] = sl * 16;
  }

  f32x4 zero = {0.f, 0.f, 0.f, 0.f};
  f32x4 acc[4][4];
#pragma unroll
  for (int i = 0; i < 4; ++i)
#pragma unroll
    for (int j = 0; j < 4; ++j) acc[i][j] = zero;

  char* Asc = (char*)As;
  char* Bsc = (char*)Bs;

#pragma unroll
  for (int t = 0; t < 4; ++t) {
    gload16(asrc[t], Asc + dsto[t]);
    gload16(bsrc[t], Bsc + dsto[t]);
    asrc[t] += 64; bsrc[t] += 64;
  }

  const int nt = K >> 6;
  for (int i = 0; i < nt; ++i) {
    const int cur = i & 1;
    if (i + 1 < nt) {
      const int nxt = cur ^ 1;
#pragma unroll
      for (int t = 0; t < 4; ++t) {
        gload16(asrc[t], Asc + nxt * 16384 + dsto[t]);
        gload16(bsrc[t], Bsc + nxt * 16384 + dsto[t]);
        asrc[t] += 64; bsrc[t] += 64;
      }
      wait_vm8();
    } else {
      wait_vm0();
    }
    barrier_raw();

    const char* Ab = Asc + cur * 16384;
    const char* Bb = Bsc + cur * 16384;
    __builtin_amdgcn_s_setprio(1);
#pragma unroll
    for (int ks = 0; ks < 2; ++ks) {
      short8 af[4], bfv[4];
#pragma unroll
      for (int mi = 0; mi < 4; ++mi) {
        int m = wr * 64 + mi * 16 + lm;
        af[mi] = *reinterpret_cast<const short8*>(
            Ab + ((m * 128 + ks * 64 + g * 16) ^ ((m & 7) << 4)));
      }
#pragma unroll
      for (int ni = 0; ni < 4; ++ni) {
        int n = wc * 64 + ni * 16 + lm;
        bfv[ni] = *reinterpret_cast<const short8*>(
            Bb + ((n * 128 + ks * 64 + g * 16) ^ ((n & 7) << 4)));
      }
#pragma unroll
      for (int mi = 0; mi < 4; ++mi)
#pragma unroll
        for (int ni = 0; ni < 4; ++ni)
          acc[mi][ni] = __builtin_amdgcn_mfma_f32_16x16x32_bf16(af[mi], bfv[ni], acc[mi][ni], 0, 0, 0);
    }
    __builtin_amdgcn_s_setprio(0);
    barrier_raw();
  }

#pragma unroll
  for (int ni = 0; ni < 4; ++ni) {
    long n = bcol + wc * 64 + ni * 16 + lm;
    float bv = bias ? bias[n] : 0.f;
#pragma unroll
    for (int mi = 0; mi < 4; ++mi) {
      long m0 = brow + wr * 64 + mi * 16 + g * 4;
#pragma unroll
      for (int r = 0; r < 4; ++r) {
        float o = acc[mi][ni][r] + bv;
        if (Cb) Cb[(m0 + r) * N + n] = __float2bfloat16(o);
        else    Cf[(m0 + r) * N + n] = o;
      }
    }
  }
}

__global__ __launch_bounds__(256) void gemm_bt(const bf16* __restrict__ A,
                                               const bf16* __restrict__ Bt,
                                               const float* __restrict__ bias,
                                               bf16* __restrict__ Cb,
                                               float* __restrict__ Cf,
                                               int N, int K) {
  __shared__ bf16 As[2 * 128 * 64];
  __shared__ bf16 Bs[2 * 128 * 64];
  int bid = blockIdx.x;
  int g = (bid & 7) * (gridDim.x >> 3) + (bid >> 3);
  gemm_core(A, Bt, bias, Cb, Cf, N, K, g & 7, g >> 3, As, Bs);
}

// ---------------- fused flash attention: 256 q-rows/block, 8 waves x 32 rows ----
// grid 512 = 64 (b,h) x 8 q-tiles; LDS 64KB -> 2 blocks/CU.
// Per wave: two 16-row groups (rg). Per s-tile: per-rg {QK^T, online softmax,
// P-store} (keeps scv[4] live per group only -> VGPR ~112), then joint PV.
__global__ __launch_bounds__(512, 4) void attn_fused(const bf16* __restrict__ q,
                                                     const bf16* __restrict__ k,
                                                     const bf16* __restrict__ vT,
                                                     bf16* __restrict__ o) {
  constexpr float C2 = 0.18033688011112042f;  // (1/8) * log2(e)
  constexpr float THR = 6.0f;
  __shared__ bf16 Kl[2][64 * 64];   // 16 KB
  __shared__ bf16 Vl[2][64 * 64];   // 16 KB
  __shared__ bf16 Pl[8][32 * 64];   // 32 KB -> 64 KB total
  const int tid = threadIdx.x;
  const int lane = tid & 63, g = lane >> 4, lm = lane & 15;
  const int wid = tid >> 6;                   // 0..7
  int bid = blockIdx.x;
  int gl = (bid & 7) * 64 + (bid >> 3);       // XCD-contiguous: 8 bh x 8 qtiles
  const int qt = gl & 7, bh = gl >> 3;
  const int b = bh >> 4, h = bh & 15;
  const int qbase = qt * 256 + wid * 32;      // wave owns 32 q rows

  // Q fragments for both row groups, pre-scaled by C2
  short8 qa[2][2];
#pragma unroll
  for (int rg = 0; rg < 2; ++rg) {
    const bf16* qrow = q + (long)(b * Lc + qbase + rg * 16 + lm) * DModel + h * 64;
    qa[rg][0] = *reinterpret_cast<const short8*>(qrow + g * 8);
    qa[rg][1] = *reinterpret_cast<const short8*>(qrow + 32 + g * 8);
#pragma unroll
    for (int j = 0; j < 8; ++j) {
      union { ushort u; bf16 h; } cv;
      cv.u = (ushort)qa[rg][0][j];
      bf16 s0 = __float2bfloat16(__bfloat162float(cv.h) * C2);
      qa[rg][0][j] = (short)*reinterpret_cast<ushort*>(&s0);
      cv.u = (ushort)qa[rg][1][j];
      bf16 s1 = __float2bfloat16(__bfloat162float(cv.h) * C2);
      qa[rg][1][j] = (short)*reinterpret_cast<ushort*>(&s1);
    }
  }

  const bf16* kbase = k + (long)b * Sc * DModel + h * 64;
  const bf16* vbase = vT + ((long)b * DModel + h * 64) * Sc;

  // staging: 512 slots of 16B per matrix, 1 slot/thread, pre-swizzled source
  const int srow = tid >> 3;
  const int scg = (tid & 7) ^ (srow & 7);
  const bf16* ksrc = kbase + (long)srow * DModel + scg * 8;
  const bf16* vsrc = vbase + (long)srow * Sc + scg * 8;
  const int dsto = tid * 16;

  f32x4 zero = {0.f, 0.f, 0.f, 0.f};
  f32x4 accO[2][4];
#pragma unroll
  for (int rg = 0; rg < 2; ++rg)
#pragma unroll
    for (int i = 0; i < 4; ++i) accO[rg][i] = zero;
  f32x4 accL[2] = {zero, zero};
  float mst[2][4] = {{-1e30f, -1e30f, -1e30f, -1e30f},
                     {-1e30f, -1e30f, -1e30f, -1e30f}};

  short8 vones;
#pragma unroll
  for (int j = 0; j < 8; ++j) vones[j] = (short)0x3F80;  // bf16 1.0

  char* Klc = (char*)Kl;
  char* Vlc = (char*)Vl;
  char* Plc = (char*)Pl + wid * (32 * 64 * 2);

  // prologue: stage tile 0 into buffer 0
  gload16(ksrc, Klc + dsto);
  gload16(vsrc, Vlc + dsto);
  ksrc += 64 * DModel; vsrc += 64;

  for (int j = 0; j < Sc / 64; ++j) {
    const int cur = j & 1;
    if (j + 1 < Sc / 64) {
      const int nxt = cur ^ 1;
      gload16(ksrc, Klc + nxt * 8192 + dsto);
      gload16(vsrc, Vlc + nxt * 8192 + dsto);
      ksrc += 64 * DModel; vsrc += 64;
      wait_vm2();   // retires tile j's 2 loads (issued last iter)
    } else {
      wait_vm0();
    }
    barrier_raw();

    const char* Kb = Klc + cur * 8192;
    const char* Vb = Vlc + cur * 8192;

    // per row-group: QK^T -> softmax -> P store (scv lives per-group only)
#pragma unroll
    for (int rg = 0; rg < 2; ++rg) {
      f32x4 scv[4];
      __builtin_amdgcn_s_setprio(1);
#pragma unroll
      for (int st = 0; st < 4; ++st) {
        int s = st * 16 + lm;
        int sw = (s & 7) << 4;
        short8 kb0 = *reinterpret_cast<const short8*>(Kb + ((s * 128 + g * 16) ^ sw));
        short8 kb1 = *reinterpret_cast<const short8*>(Kb + ((s * 128 + 64 + g * 16) ^ sw));
        f32x4 z = zero;
        z = __builtin_amdgcn_mfma_f32_16x16x32_bf16(qa[rg][0], kb0, z, 0, 0, 0);
        z = __builtin_amdgcn_mfma_f32_16x16x32_bf16(qa[rg][1], kb1, z, 0, 0, 0);
        scv[st] = z;
      }
      __builtin_amdgcn_s_setprio(0);

      float pmax[4];
#pragma unroll
      for (int r = 0; r < 4; ++r)
        pmax[r] = fmaxf(fmaxf(scv[0][r], scv[1][r]), fmaxf(scv[2][r], scv[3][r]));
      int need = 0;
#pragma unroll
      for (int r = 0; r < 4; ++r) need |= (pmax[r] > mst[rg][r] + THR) ? 1 : 0;
      if (__any(need)) {
#pragma unroll
        for (int r = 0; r < 4; ++r) {
          float mx = pmax[r];
          mx = fmaxf(mx, __shfl_xor(mx, 1));
          mx = fmaxf(mx, __shfl_xor(mx, 2));
          mx = fmaxf(mx, __shfl_xor(mx, 4));
          mx = fmaxf(mx, __shfl_xor(mx, 8));
          float mnew = fmaxf(mst[rg][r], mx);
          float corr = __builtin_amdgcn_exp2f(mst[rg][r] - mnew);
          mst[rg][r] = mnew;
          accL[rg][r] *= corr;
#pragma unroll
          for (int et = 0; et < 4; ++et) accO[rg][et][r] *= corr;
        }
      }
#pragma unroll
      for (int r = 0; r < 4; ++r) {
        int pq = rg * 16 + g * 4 + r;
        int swp = (pq & 7) << 4;
#pragma unroll
        for (int st = 0; st < 4; ++st) {
          float p = __builtin_amdgcn_exp2f(scv[st][r] - mst[rg][r]);
          *reinterpret_cast<bf16*>(Plc + ((pq * 128 + (st * 16 + lm) * 2) ^ swp)) =
              __float2bfloat16(p);
        }
      }
    }

    // joint PV over both row groups: V frags loaded once, used twice
    __builtin_amdgcn_s_setprio(1);
#pragma unroll
    for (int sk = 0; sk < 2; ++sk) {
      short8 pa[2];
#pragma unroll
      for (int rg = 0; rg < 2; ++rg) {
        int pr = rg * 16 + lm;
        pa[rg] = *reinterpret_cast<const short8*>(
            Plc + ((pr * 128 + sk * 64 + g * 16) ^ ((pr & 7) << 4)));
      }
      accL[0] = __builtin_amdgcn_mfma_f32_16x16x32_bf16(pa[0], vones, accL[0], 0, 0, 0);
      accL[1] = __builtin_amdgcn_mfma_f32_16x16x32_bf16(pa[1], vones, accL[1], 0, 0, 0);
#pragma unroll
      for (int et = 0; et < 4; ++et) {
        int e = et * 16 + lm;
        short8 vb = *reinterpret_cast<const short8*>(
            Vb + ((e * 128 + sk * 64 + g * 16) ^ ((e & 7) << 4)));
        accO[0][et] = __builtin_amdgcn_mfma_f32_16x16x32_bf16(pa[0], vb, accO[0][et], 0, 0, 0);
        accO[1][et] = __builtin_amdgcn_mfma_f32_16x16x32_bf16(pa[1], vb, accO[1][et], 0, 0, 0);
      }
    }
    __builtin_amdgcn_s_setprio(0);
    barrier_raw();
  }

#pragma unroll
  for (int rg = 0; rg < 2; ++rg)
#pragma unroll
    for (int r = 0; r < 4; ++r) {
      float inv = 1.0f / accL[rg][r];
      long row = (long)(b * Lc + qbase + rg * 16 + g * 4 + r);
#pragma unroll
      for (int et = 0; et < 4; ++et)
        o[row * DModel + h * 64 + et * 16 + lm] = __float2bfloat16(accO[rg][et][r] * inv);
    }
}

// ---------------- host launch ----------------
extern "C" void kernel_launch(void* const* d_in, const int* in_sizes, int n_in,
                              void* d_out, int out_size, void* d_ws, size_t ws_size,
                              hipStream_t stream) {
  const float* tgt = (const float*)d_in[0];
  const float* src = (const float*)d_in[1];
  const float* val = (const float*)d_in[2];
  const float* Wq  = (const float*)d_in[3];
  const float* bq  = (const float*)d_in[4];
  const float* Wk  = (const float*)d_in[5];
  const float* bk  = (const float*)d_in[6];
  const float* Wv  = (const float*)d_in[7];
  const float* bv  = (const float*)d_in[8];
  const float* Wo  = (const float*)d_in[9];
  const float* bo  = (const float*)d_in[10];
  float* out = (float*)d_out;
  char* ws = (char*)d_ws;

  const long n4_tgt = (long)8192 * 1024 / 4;
  const long n4_sv  = (long)4096 * 4096 / 4;

  if (ws_size < (132ul << 20)) return;

  bf16* WqT  = (bf16*)(ws + (0l   << 20));  // 2 MB
  bf16* WkT  = (bf16*)(ws + (2l   << 20));  // 8 MB
  bf16* WvT  = (bf16*)(ws + (10l  << 20));  // 8 MB
  bf16* WoT  = (bf16*)(ws + (18l  << 20));  // 2 MB
  bf16* tgtb = (bf16*)(ws + (20l  << 20));  // 16 MB (attn out aliases later)
  bf16* srcb = (bf16*)(ws + (36l  << 20));  // 32 MB
  bf16* valb = (bf16*)(ws + (68l  << 20));  // 32 MB
  bf16* qb   = (bf16*)(ws + (100l << 20));  // 16 MB
  bf16* kb   = (bf16*)(ws + (116l << 20));  // 8 MB
  bf16* vTb  = (bf16*)(ws + (124l << 20));  // 8 MB [4][1024][1024] -> 132 MB
  bf16* attnb = tgtb;  // tgtb dead after QKV gemm

  // weights transpose + activation cvt, single launch
  prep<<<10240 + 4096, 256, 0, stream>>>(Wq, WqT, Wk, WkT, Wv, WvT, Wo, WoT,
                                         tgt, tgtb, n4_tgt, src, srcb, n4_sv,
                                         val, valb, n4_sv);
  // balanced grid: K 128 (nt=128) + V 128 (nt=128) + Q 256 (nt=32) = 512 = 2/CU
  gemm_qkv_bal<<<512, 512, 0, stream>>>(srcb, WkT, bk, kb, 4096, 128,
                                        valb, WvT, bv, vTb, 4096, 128,
                                        tgtb, WqT, bq, qb, 1024);
  attn_fused<<<512, 512, 0, stream>>>(qb, kb, vTb, attnb);
  gemm_bt<<<512, 256, 0, stream>>>(attnb, WoT, bo, (bf16*)nullptr, out, 1024, 1024);
}

// Round 15
// 223.787 us; speedup vs baseline: 1.0383x; 1.0383x over previous
//
#include <hip/hip_runtime.h>
#include <hip/hip_bf16.h>

using bf16 = __hip_bfloat16;
typedef __attribute__((ext_vector_type(8))) short short8;
typedef __attribute__((ext_vector_type(4))) float f32x4;

static constexpr int Bc = 4, Lc = 2048, Sc = 1024;
static constexpr int DModel = 1024;

__device__ __forceinline__ void gload16(const void* g, void* l) {
  __builtin_amdgcn_global_load_lds((const __attribute__((address_space(1))) void*)g,
                                   (__attribute__((address_space(3))) void*)l,
                                   16, 0, 0);
}

__device__ __forceinline__ void wait_vm3()  { asm volatile("s_waitcnt vmcnt(3)" ::: "memory"); }
__device__ __forceinline__ void wait_vm0()  { asm volatile("s_waitcnt vmcnt(0)" ::: "memory"); }
__device__ __forceinline__ void barrier_raw() { asm volatile("s_barrier" ::: "memory"); }

// ---------------- prep: weight transposes + activation conversions, ONE launch --
__global__ __launch_bounds__(256) void prep(
    const float* __restrict__ Wq, bf16* __restrict__ WqT,
    const float* __restrict__ Wk, bf16* __restrict__ WkT,
    const float* __restrict__ Wv, bf16* __restrict__ WvT,
    const float* __restrict__ Wo, bf16* __restrict__ WoT,
    const float* __restrict__ a, bf16* __restrict__ ao, long na4,
    const float* __restrict__ b, bf16* __restrict__ bo, long nb4,
    const float* __restrict__ c, bf16* __restrict__ co, long nc4) {
  __shared__ bf16 tile[32][33];
  int bid = blockIdx.x;
  if (bid < 10240) {
    const float* in; bf16* out; int R, l;
    if (bid < 1024)      { in = Wq; out = WqT; R = 1024; l = bid; }
    else if (bid < 5120) { in = Wk; out = WkT; R = 4096; l = bid - 1024; }
    else if (bid < 9216) { in = Wv; out = WvT; R = 4096; l = bid - 5120; }
    else                 { in = Wo; out = WoT; R = 1024; l = bid - 9216; }
    const int C = 1024;
    int bx = l & 31, by = l >> 5;
    int tx = threadIdx.x & 31, ty = threadIdx.x >> 5;
    int r0 = by * 32, c0 = bx * 32;
#pragma unroll
    for (int i = 0; i < 32; i += 8)
      tile[ty + i][tx] = __float2bfloat16(in[(long)(r0 + ty + i) * C + c0 + tx]);
    __syncthreads();
#pragma unroll
    for (int i = 0; i < 32; i += 8)
      out[(long)(c0 + ty + i) * R + r0 + tx] = tile[tx][ty + i];
  } else {
    int cb = bid - 10240;
    long total = na4 + nb4 + nc4;
    long stride = (long)(gridDim.x - 10240) * blockDim.x;
    for (long i = (long)cb * blockDim.x + threadIdx.x; i < total; i += stride) {
      const float* src; bf16* dst; long j;
      if (i < na4)            { src = a; dst = ao; j = i; }
      else if (i < na4 + nb4) { src = b; dst = bo; j = i - na4; }
      else                    { src = c; dst = co; j = i - na4 - nb4; }
      float4 v = reinterpret_cast<const float4*>(src)[j];
      alignas(8) bf16 t[4] = {__float2bfloat16(v.x), __float2bfloat16(v.y),
                              __float2bfloat16(v.z), __float2bfloat16(v.w)};
      reinterpret_cast<ushort4*>(dst)[j] = *reinterpret_cast<const ushort4*>(t);
    }
  }
}

// ======== balanced QKV GEMM: 256x128 tile, BK=32, 8 waves, 3-deep LDS ========
// SINGLE-BARRIER schedule: {wait vm3 (certify tile t); barrier; STAGE(t+2);
// ds_read+MFMA}. WAR on buf (t+2)%3 = (t-1)%3 is safe because every wave's
// ds_reads of buf(t-1) retired (compiler lgkmcnt waits before consuming MFMAs)
// before it reached barrier(t). FIFO: outstanding at wait = {S(t),S(t+1)}=6,
// vm3 retires S(t); S staged 2 iterations before consumption.
__device__ __forceinline__ void gemm_bal_core(const bf16* __restrict__ A, const bf16* __restrict__ Bt,
                                              const float* __restrict__ bias,
                                              bf16* __restrict__ Cb, bf16* __restrict__ Cvt,
                                              int K, int bx, int by, bf16* lds) {
  const int tid = threadIdx.x;
  const int lane = tid & 63, g = lane >> 4, lm = lane & 15;
  const int wid = tid >> 6, wr = wid >> 1, wc = wid & 1;  // 4M x 2N waves, 64x64 each
  const long brow = (long)by * 256, bcol = (long)bx * 128;

  char* L = (char*)lds;
  const int rowA = tid >> 2;
  const int kg = (tid & 3) ^ ((rowA >> 1) & 3);  // source pre-swizzle
  const bf16* aS = A + (brow + rowA) * (long)K + kg * 8;
  const bf16* bS = Bt + (bcol + rowA) * (long)K + kg * 8;
  const long aOff1 = 128l * K;
  const int dA = tid * 16;

#define STAGEB(t_) {                                                     \
    const int _b = (t_) % 3; const long _ko = (long)(t_) * 32;           \
    gload16(aS + _ko,         L + _b * 24576 + dA);                      \
    gload16(aS + aOff1 + _ko, L + _b * 24576 + 8192 + dA);               \
    gload16(bS + _ko,         L + _b * 24576 + 16384 + dA); }

  f32x4 zero = {0.f, 0.f, 0.f, 0.f};
  f32x4 acc[4][4];
#pragma unroll
  for (int i = 0; i < 4; ++i)
#pragma unroll
    for (int j = 0; j < 4; ++j) acc[i][j] = zero;

  STAGEB(0);
  STAGEB(1);   // 6 loads in flight

  const int nt = K >> 5;
  for (int t = 0; t < nt; ++t) {
    if (t + 1 < nt) wait_vm3();  // retires S(t), keeps S(t+1)
    else            wait_vm0();  // last tile
    barrier_raw();               // tile t resident block-wide; reads of buf(t-1) retired
    if (t + 2 < nt) STAGEB(t + 2);  // overwrites buf (t-1)%3 -- safe post-barrier

    const char* Bf = L + (t % 3) * 24576;
    short8 aR[4], bR[4];
#pragma unroll
    for (int mi = 0; mi < 4; ++mi) {
      const int r = wr * 64 + mi * 16 + lm;
      aR[mi] = *reinterpret_cast<const short8*>(
          Bf + r * 64 + ((g ^ ((r >> 1) & 3)) << 4));
    }
#pragma unroll
    for (int ni = 0; ni < 4; ++ni) {
      const int r = wc * 64 + ni * 16 + lm;
      bR[ni] = *reinterpret_cast<const short8*>(
          Bf + 16384 + r * 64 + ((g ^ ((r >> 1) & 3)) << 4));
    }
    __builtin_amdgcn_s_setprio(1);
#pragma unroll
    for (int mi = 0; mi < 4; ++mi)
#pragma unroll
      for (int ni = 0; ni < 4; ++ni)
        acc[mi][ni] = __builtin_amdgcn_mfma_f32_16x16x32_bf16(aR[mi], bR[ni], acc[mi][ni], 0, 0, 0);
    __builtin_amdgcn_s_setprio(0);
  }
#undef STAGEB

#pragma unroll
  for (int ni = 0; ni < 4; ++ni) {
    long n = bcol + wc * 64 + ni * 16 + lm;
    float bv = bias ? bias[n] : 0.f;
#pragma unroll
    for (int mi = 0; mi < 4; ++mi) {
      long m0 = brow + wr * 64 + mi * 16 + g * 4;
      if (Cvt) {  // V-proj: write vT [b][n][s]
        long b = m0 >> 10, s0 = m0 & 1023;
        alignas(8) bf16 t4[4];
#pragma unroll
        for (int r = 0; r < 4; ++r) t4[r] = __float2bfloat16(acc[mi][ni][r] + bv);
        *reinterpret_cast<ushort4*>(Cvt + ((b << 10) + n) * 1024 + s0) =
            *reinterpret_cast<const ushort4*>(t4);
      } else {
#pragma unroll
        for (int r = 0; r < 4; ++r)
          Cb[(m0 + r) * 1024 + n] = __float2bfloat16(acc[mi][ni][r] + bv);
      }
    }
  }
}

// QKV fused, balanced: K 128 blocks (nt=128), V 128 (nt=128), Q 256 (nt=32).
__global__ __launch_bounds__(512, 4) void gemm_qkv_bal(
    const bf16* __restrict__ Ak, const bf16* __restrict__ Bk, const float* __restrict__ bk_, bf16* __restrict__ Ck, int Kk, int nbk,
    const bf16* __restrict__ Av, const bf16* __restrict__ Bv_, const float* __restrict__ bv_, bf16* __restrict__ CvT, int Kv, int nbv,
    const bf16* __restrict__ Aq, const bf16* __restrict__ Bq_, const float* __restrict__ bq_, bf16* __restrict__ Cq, int Kq) {
  __shared__ bf16 lds[36864];  // 72 KB
  int bid = blockIdx.x;
  const bf16 *A, *Bt; const float* bias; bf16 *C = nullptr, *Cvt = nullptr; int K, l, nb;
  if (bid < nbk)            { A = Ak; Bt = Bk;  bias = bk_; C = Ck;    K = Kk; l = bid;             nb = nbk; }
  else if (bid < nbk + nbv) { A = Av; Bt = Bv_; bias = bv_; Cvt = CvT; K = Kv; l = bid - nbk;       nb = nbv; }
  else                      { A = Aq; Bt = Bq_; bias = bq_; C = Cq;   K = Kq; l = bid - nbk - nbv; nb = gridDim.x - nbk - nbv; }
  int g = (l & 7) * (nb >> 3) + (l >> 3);
  gemm_bal_core(A, Bt, bias, C, Cvt, K, g & 7, g >> 3, lds);
}

// ---------------- 128^2 GEMM (2-buffer, single-barrier) for O-proj ----------
// {wait vm0 (certify tile i, staged last iter); barrier; STAGE(i+1); compute}.
__device__ __forceinline__ void gemm_core(const bf16* __restrict__ A, const bf16* __restrict__ Bt,
                                          const float* __restrict__ bias,
                                          bf16* __restrict__ Cb, float* __restrict__ Cf,
                                          int N, int K, int bx, int by,
                                          bf16* As, bf16* Bs) {
  const int tid = threadIdx.x;
  const int lane = tid & 63, g = lane >> 4, lm = lane & 15;
  const int wid = tid >> 6, wr = wid >> 1, wc = wid & 1;
  const long brow = (long)by * 128, bcol = (long)bx * 128;

  const bf16* asrc[4];
  const bf16* bsrc[4];
  int dsto[4];
#pragma unroll
  for (int t = 0; t < 4; ++t) {
    int sl = tid + t * 256;
    int row = sl >> 3;
    int kg = (sl & 7) ^ (row & 7);
    asrc[t] = A + (brow + row) * (long)K + kg * 8;
    bsrc[t] = Bt + (bcol + row) * (long)K + kg * 8;
    dsto[t] = sl * 16;
  }

  f32x4 zero = {0.f, 0.f, 0.f, 0.f};
  f32x4 acc[4][4];
#pragma unroll
  for (int i = 0; i < 4; ++i)
#pragma unroll
    for (int j = 0; j < 4; ++j) acc[i][j] = zero;

  char* Asc = (char*)As;
  char* Bsc = (char*)Bs;

  // prologue: stage tile 0 into buffer 0
#pragma unroll
  for (int t = 0; t < 4; ++t) {
    gload16(asrc[t], Asc + dsto[t]);
    gload16(bsrc[t], Bsc + dsto[t]);
    asrc[t] += 64; bsrc[t] += 64;
  }

  const int nt = K >> 6;
  for (int i = 0; i < nt; ++i) {
    wait_vm0();      // certify tile i (staged one iter ago)
    barrier_raw();   // resident block-wide; reads of buf(i-1) retired
    if (i + 1 < nt) {
      const int nxt = (i + 1) & 1;
#pragma unroll
      for (int t = 0; t < 4; ++t) {
        gload16(asrc[t], Asc + nxt * 16384 + dsto[t]);
        gload16(bsrc[t], Bsc + nxt * 16384 + dsto[t]);
        asrc[t] += 64; bsrc[t] += 64;
      }
    }

    const char* Ab = Asc + (i & 1) * 16384;
    const char* Bb = Bsc + (i & 1) * 16384;
    __builtin_amdgcn_s_setprio(1);
#pragma unroll
    for (int ks = 0; ks < 2; ++ks) {
      short8 af[4], bfv[4];
#pragma unroll
      for (int mi = 0; mi < 4; ++mi) {
        int m = wr * 64 + mi * 16 + lm;
        af[mi] = *reinterpret_cast<const short8*>(
            Ab + ((m * 128 + ks * 64 + g * 16) ^ ((m & 7) << 4)));
      }
#pragma unroll
      for (int ni = 0; ni < 4; ++ni) {
        int n = wc * 64 + ni * 16 + lm;
        bfv[ni] = *reinterpret_cast<const short8*>(
            Bb + ((n * 128 + ks * 64 + g * 16) ^ ((n & 7) << 4)));
      }
#pragma unroll
      for (int mi = 0; mi < 4; ++mi)
#pragma unroll
        for (int ni = 0; ni < 4; ++ni)
          acc[mi][ni] = __builtin_amdgcn_mfma_f32_16x16x32_bf16(af[mi], bfv[ni], acc[mi][ni], 0, 0, 0);
    }
    __builtin_amdgcn_s_setprio(0);
  }

#pragma unroll
  for (int ni = 0; ni < 4; ++ni) {
    long n = bcol + wc * 64 + ni * 16 + lm;
    float bv = bias ? bias[n] : 0.f;
#pragma unroll
    for (int mi = 0; mi < 4; ++mi) {
      long m0 = brow + wr * 64 + mi * 16 + g * 4;
#pragma unroll
      for (int r = 0; r < 4; ++r) {
        float o = acc[mi][ni][r] + bv;
        if (Cb) Cb[(m0 + r) * N + n] = __float2bfloat16(o);
        else    Cf[(m0 + r) * N + n] = o;
      }
    }
  }
}

__global__ __launch_bounds__(256) void gemm_bt(const bf16* __restrict__ A,
                                               const bf16* __restrict__ Bt,
                                               const float* __restrict__ bias,
                                               bf16* __restrict__ Cb,
                                               float* __restrict__ Cf,
                                               int N, int K) {
  __shared__ bf16 As[2 * 128 * 64];
  __shared__ bf16 Bs[2 * 128 * 64];
  int bid = blockIdx.x;
  int g = (bid & 7) * (gridDim.x >> 3) + (bid >> 3);
  gemm_core(A, Bt, bias, Cb, Cf, N, K, g & 7, g >> 3, As, Bs);
}

// ---------------- fused flash attention: 128 q-rows/block, 8 waves ----------
// (R12's best version + single-barrier schedule.)
__global__ __launch_bounds__(512) void attn_fused(const bf16* __restrict__ q,
                                                  const bf16* __restrict__ k,
                                                  const bf16* __restrict__ vT,
                                                  bf16* __restrict__ o) {
  constexpr float C2 = 0.18033688011112042f;  // (1/8) * log2(e)
  constexpr float THR = 6.0f;
  __shared__ bf16 Kl[2][64 * 64];   // 16 KB
  __shared__ bf16 Vl[2][64 * 64];   // 16 KB
  __shared__ bf16 Pl[8][16 * 64];   // 16 KB
  const int tid = threadIdx.x;
  const int lane = tid & 63, g = lane >> 4, lm = lane & 15;
  const int wid = tid >> 6;
  int bid = blockIdx.x;
  int gl = (bid & 7) * 128 + (bid >> 3);
  const int qt = gl & 15, bh = gl >> 4;
  const int b = bh >> 4, h = bh & 15;
  const int qbase = qt * 128 + wid * 16;

  const bf16* qrow = q + (long)(b * Lc + qbase + lm) * DModel + h * 64;
  short8 qa0 = *reinterpret_cast<const short8*>(qrow + g * 8);
  short8 qa1 = *reinterpret_cast<const short8*>(qrow + 32 + g * 8);
#pragma unroll
  for (int j = 0; j < 8; ++j) {
    union { ushort u; bf16 h; } cv;
    cv.u = (ushort)qa0[j];
    bf16 s0 = __float2bfloat16(__bfloat162float(cv.h) * C2);
    qa0[j] = (short)*reinterpret_cast<ushort*>(&s0);
    cv.u = (ushort)qa1[j];
    bf16 s1 = __float2bfloat16(__bfloat162float(cv.h) * C2);
    qa1[j] = (short)*reinterpret_cast<ushort*>(&s1);
  }

  const bf16* kbase = k + (long)b * Sc * DModel + h * 64;
  const bf16* vbase = vT + ((long)b * DModel + h * 64) * Sc;

  const int srow = tid >> 3;
  const int scg = (tid & 7) ^ (srow & 7);
  const bf16* ksrc = kbase + (long)srow * DModel + scg * 8;
  const bf16* vsrc = vbase + (long)srow * Sc + scg * 8;
  const int dsto = tid * 16;

  f32x4 zero = {0.f, 0.f, 0.f, 0.f};
  f32x4 accO[4];
#pragma unroll
  for (int i = 0; i < 4; ++i) accO[i] = zero;
  f32x4 accL = zero;
  float mst[4] = {-1e30f, -1e30f, -1e30f, -1e30f};

  short8 vones;
#pragma unroll
  for (int j = 0; j < 8; ++j) vones[j] = (short)0x3F80;

  char* Klc = (char*)Kl;
  char* Vlc = (char*)Vl;
  char* Plc = (char*)Pl + wid * (16 * 64 * 2);

  // prologue: stage tile 0 into buffer 0
  gload16(ksrc, Klc + dsto);
  gload16(vsrc, Vlc + dsto);
  ksrc += 64 * DModel; vsrc += 64;

  for (int j = 0; j < Sc / 64; ++j) {
    const int cur = j & 1;
    wait_vm0();      // certify tile j (staged one iter ago)
    barrier_raw();   // resident; reads of buf(j-1) retired
    if (j + 1 < Sc / 64) {
      const int nxt = cur ^ 1;
      gload16(ksrc, Klc + nxt * 8192 + dsto);
      gload16(vsrc, Vlc + nxt * 8192 + dsto);
      ksrc += 64 * DModel; vsrc += 64;
    }

    const char* Kb = Klc + cur * 8192;
    const char* Vb = Vlc + cur * 8192;

    f32x4 scv[4];
    __builtin_amdgcn_s_setprio(1);
#pragma unroll
    for (int st = 0; st < 4; ++st) {
      int s = st * 16 + lm;
      int sw = (s & 7) << 4;
      short8 kb0 = *reinterpret_cast<const short8*>(Kb + ((s * 128 + g * 16) ^ sw));
      short8 kb1 = *reinterpret_cast<const short8*>(Kb + ((s * 128 + 64 + g * 16) ^ sw));
      f32x4 z = zero;
      z = __builtin_amdgcn_mfma_f32_16x16x32_bf16(qa0, kb0, z, 0, 0, 0);
      z = __builtin_amdgcn_mfma_f32_16x16x32_bf16(qa1, kb1, z, 0, 0, 0);
      scv[st] = z;
    }
    __builtin_amdgcn_s_setprio(0);

    float pmax[4];
#pragma unroll
    for (int r = 0; r < 4; ++r)
      pmax[r] = fmaxf(fmaxf(scv[0][r], scv[1][r]), fmaxf(scv[2][r], scv[3][r]));
    int need = 0;
#pragma unroll
    for (int r = 0; r < 4; ++r) need |= (pmax[r] > mst[r] + THR) ? 1 : 0;
    if (__any(need)) {
#pragma unroll
      for (int r = 0; r < 4; ++r) {
        float mx = pmax[r];
        mx = fmaxf(mx, __shfl_xor(mx, 1));
        mx = fmaxf(mx, __shfl_xor(mx, 2));
        mx = fmaxf(mx, __shfl_xor(mx, 4));
        mx = fmaxf(mx, __shfl_xor(mx, 8));
        float mnew = fmaxf(mst[r], mx);
        float corr = __builtin_amdgcn_exp2f(mst[r] - mnew);
        mst[r] = mnew;
        accL[r] *= corr;
#pragma unroll
        for (int et = 0; et < 4; ++et) accO[et][r] *= corr;
      }
    }
#pragma unroll
    for (int r = 0; r < 4; ++r) {
      int qq = g * 4 + r;
      int swp = (qq & 7) << 4;
#pragma unroll
      for (int st = 0; st < 4; ++st) {
        float p = __builtin_amdgcn_exp2f(scv[st][r] - mst[r]);
        *reinterpret_cast<bf16*>(Plc + ((qq * 128 + (st * 16 + lm) * 2) ^ swp)) =
            __float2bfloat16(p);
      }
    }

    __builtin_amdgcn_s_setprio(1);
#pragma unroll
    for (int sk = 0; sk < 2; ++sk) {
      short8 pa = *reinterpret_cast<const short8*>(
          Plc + ((lm * 128 + sk * 64 + g * 16) ^ ((lm & 7) << 4)));
      accL = __builtin_amdgcn_mfma_f32_16x16x32_bf16(pa, vones, accL, 0, 0, 0);
#pragma unroll
      for (int et = 0; et < 4; ++et) {
        int e = et * 16 + lm;
        short8 vb = *reinterpret_cast<const short8*>(
            Vb + ((e * 128 + sk * 64 + g * 16) ^ ((e & 7) << 4)));
        accO[et] = __builtin_amdgcn_mfma_f32_16x16x32_bf16(pa, vb, accO[et], 0, 0, 0);
      }
    }
    __builtin_amdgcn_s_setprio(0);
  }

#pragma unroll
  for (int r = 0; r < 4; ++r) {
    float inv = 1.0f / accL[r];
    long row = (long)(b * Lc + qbase + g * 4 + r);
#pragma unroll
    for (int et = 0; et < 4; ++et)
      o[row * DModel + h * 64 + et * 16 + lm] = __float2bfloat16(accO[et][r] * inv);
  }
}

// ---------------- host launch ----------------
extern "C" void kernel_launch(void* const* d_in, const int* in_sizes, int n_in,
                              void* d_out, int out_size, void* d_ws, size_t ws_size,
                              hipStream_t stream) {
  const float* tgt = (const float*)d_in[0];
  const float* src = (const float*)d_in[1];
  const float* val = (const float*)d_in[2];
  const float* Wq  = (const float*)d_in[3];
  const float* bq  = (const float*)d_in[4];
  const float* Wk  = (const float*)d_in[5];
  const float* bk  = (const float*)d_in[6];
  const float* Wv  = (const float*)d_in[7];
  const float* bv  = (const float*)d_in[8];
  const float* Wo  = (const float*)d_in[9];
  const float* bo  = (const float*)d_in[10];
  float* out = (float*)d_out;
  char* ws = (char*)d_ws;

  const long n4_tgt = (long)8192 * 1024 / 4;
  const long n4_sv  = (long)4096 * 4096 / 4;

  if (ws_size < (132ul << 20)) return;

  bf16* WqT  = (bf16*)(ws + (0l   << 20));  // 2 MB
  bf16* WkT  = (bf16*)(ws + (2l   << 20));  // 8 MB
  bf16* WvT  = (bf16*)(ws + (10l  << 20));  // 8 MB
  bf16* WoT  = (bf16*)(ws + (18l  << 20));  // 2 MB
  bf16* tgtb = (bf16*)(ws + (20l  << 20));  // 16 MB (attn out aliases later)
  bf16* srcb = (bf16*)(ws + (36l  << 20));  // 32 MB
  bf16* valb = (bf16*)(ws + (68l  << 20));  // 32 MB
  bf16* qb   = (bf16*)(ws + (100l << 20));  // 16 MB
  bf16* kb   = (bf16*)(ws + (116l << 20));  // 8 MB
  bf16* vTb  = (bf16*)(ws + (124l << 20));  // 8 MB [4][1024][1024] -> 132 MB
  bf16* attnb = tgtb;  // tgtb dead after QKV gemm

  prep<<<10240 + 4096, 256, 0, stream>>>(Wq, WqT, Wk, WkT, Wv, WvT, Wo, WoT,
                                         tgt, tgtb, n4_tgt, src, srcb, n4_sv,
                                         val, valb, n4_sv);
  gemm_qkv_bal<<<512, 512, 0, stream>>>(srcb, WkT, bk, kb, 4096, 128,
                                        valb, WvT, bv, vTb, 4096, 128,
                                        tgtb, WqT, bq, qb, 1024);
  attn_fused<<<1024, 512, 0, stream>>>(qb, kb, vTb, attnb);
  gemm_bt<<<512, 256, 0, stream>>>(attnb, WoT, bo, (bf16*)nullptr, out, 1024, 1024);
}

// Round 16
// 220.031 us; speedup vs baseline: 1.0560x; 1.0171x over previous
//
#include <hip/hip_runtime.h>
#include <hip/hip_bf16.h>

using bf16 = __hip_bfloat16;
typedef __attribute__((ext_vector_type(8))) short short8;
typedef __attribute__((ext_vector_type(4))) float f32x4;

static constexpr int Bc = 4, Lc = 2048, Sc = 1024;
static constexpr int DModel = 1024;

__device__ __forceinline__ void gload16(const void* g, void* l) {
  __builtin_amdgcn_global_load_lds((const __attribute__((address_space(1))) void*)g,
                                   (__attribute__((address_space(3))) void*)l,
                                   16, 0, 0);
}

__device__ __forceinline__ void wait_vm3()  { asm volatile("s_waitcnt vmcnt(3)" ::: "memory"); }
__device__ __forceinline__ void wait_vm0()  { asm volatile("s_waitcnt vmcnt(0)" ::: "memory"); }
__device__ __forceinline__ void barrier_raw() { asm volatile("s_barrier" ::: "memory"); }

// ---------------- prep: weight transposes + activation conversions, ONE launch --
__global__ __launch_bounds__(256) void prep(
    const float* __restrict__ Wq, bf16* __restrict__ WqT,
    const float* __restrict__ Wk, bf16* __restrict__ WkT,
    const float* __restrict__ Wv, bf16* __restrict__ WvT,
    const float* __restrict__ Wo, bf16* __restrict__ WoT,
    const float* __restrict__ a, bf16* __restrict__ ao, long na4,
    const float* __restrict__ b, bf16* __restrict__ bo, long nb4,
    const float* __restrict__ c, bf16* __restrict__ co, long nc4) {
  __shared__ bf16 tile[32][33];
  int bid = blockIdx.x;
  if (bid < 10240) {
    const float* in; bf16* out; int R, l;
    if (bid < 1024)      { in = Wq; out = WqT; R = 1024; l = bid; }
    else if (bid < 5120) { in = Wk; out = WkT; R = 4096; l = bid - 1024; }
    else if (bid < 9216) { in = Wv; out = WvT; R = 4096; l = bid - 5120; }
    else                 { in = Wo; out = WoT; R = 1024; l = bid - 9216; }
    const int C = 1024;
    int bx = l & 31, by = l >> 5;
    int tx = threadIdx.x & 31, ty = threadIdx.x >> 5;
    int r0 = by * 32, c0 = bx * 32;
#pragma unroll
    for (int i = 0; i < 32; i += 8)
      tile[ty + i][tx] = __float2bfloat16(in[(long)(r0 + ty + i) * C + c0 + tx]);
    __syncthreads();
#pragma unroll
    for (int i = 0; i < 32; i += 8)
      out[(long)(c0 + ty + i) * R + r0 + tx] = tile[tx][ty + i];
  } else {
    int cb = bid - 10240;
    long total = na4 + nb4 + nc4;
    long stride = (long)(gridDim.x - 10240) * blockDim.x;
    for (long i = (long)cb * blockDim.x + threadIdx.x; i < total; i += stride) {
      const float* src; bf16* dst; long j;
      if (i < na4)            { src = a; dst = ao; j = i; }
      else if (i < na4 + nb4) { src = b; dst = bo; j = i - na4; }
      else                    { src = c; dst = co; j = i - na4 - nb4; }
      float4 v = reinterpret_cast<const float4*>(src)[j];
      alignas(8) bf16 t[4] = {__float2bfloat16(v.x), __float2bfloat16(v.y),
                              __float2bfloat16(v.z), __float2bfloat16(v.w)};
      reinterpret_cast<ushort4*>(dst)[j] = *reinterpret_cast<const ushort4*>(t);
    }
  }
}

// ======== balanced QKV GEMM: 256x128 tile, BK=32, 8 waves, 3-deep LDS ========
// Single-barrier schedule, critical-path-first issue order:
// {vm3 (certify t); barrier; ds_read frags (critical path); STAGE(t+2); MFMA}.
// No setprio: lockstep GEMM (T5 is null-to-negative here per m190; it also
// deprioritizes the co-resident block's staging waves).
__device__ __forceinline__ void gemm_bal_core(const bf16* __restrict__ A, const bf16* __restrict__ Bt,
                                              const float* __restrict__ bias,
                                              bf16* __restrict__ Cb, bf16* __restrict__ Cvt,
                                              int K, int bx, int by, bf16* lds) {
  const int tid = threadIdx.x;
  const int lane = tid & 63, g = lane >> 4, lm = lane & 15;
  const int wid = tid >> 6, wr = wid >> 1, wc = wid & 1;  // 4M x 2N waves, 64x64 each
  const long brow = (long)by * 256, bcol = (long)bx * 128;

  char* L = (char*)lds;
  const int rowA = tid >> 2;
  const int kg = (tid & 3) ^ ((rowA >> 1) & 3);  // source pre-swizzle
  const bf16* aS = A + (brow + rowA) * (long)K + kg * 8;
  const bf16* bS = Bt + (bcol + rowA) * (long)K + kg * 8;
  const long aOff1 = 128l * K;
  const int dA = tid * 16;

#define STAGEB(t_) {                                                     \
    const int _b = (t_) % 3; const long _ko = (long)(t_) * 32;           \
    gload16(aS + _ko,         L + _b * 24576 + dA);                      \
    gload16(aS + aOff1 + _ko, L + _b * 24576 + 8192 + dA);               \
    gload16(bS + _ko,         L + _b * 24576 + 16384 + dA); }

  f32x4 zero = {0.f, 0.f, 0.f, 0.f};
  f32x4 acc[4][4];
#pragma unroll
  for (int i = 0; i < 4; ++i)
#pragma unroll
    for (int j = 0; j < 4; ++j) acc[i][j] = zero;

  STAGEB(0);
  STAGEB(1);   // 6 loads in flight

  const int nt = K >> 5;
  for (int t = 0; t < nt; ++t) {
    if (t + 1 < nt) wait_vm3();  // retires S(t), keeps S(t+1)
    else            wait_vm0();  // last tile
    barrier_raw();               // tile t resident block-wide; reads of buf(t-1) retired

    // critical-path ds_reads first (MFMAs wait on these via lgkmcnt)
    const char* Bf = L + (t % 3) * 24576;
    short8 aR[4], bR[4];
#pragma unroll
    for (int mi = 0; mi < 4; ++mi) {
      const int r = wr * 64 + mi * 16 + lm;
      aR[mi] = *reinterpret_cast<const short8*>(
          Bf + r * 64 + ((g ^ ((r >> 1) & 3)) << 4));
    }
#pragma unroll
    for (int ni = 0; ni < 4; ++ni) {
      const int r = wc * 64 + ni * 16 + lm;
      bR[ni] = *reinterpret_cast<const short8*>(
          Bf + 16384 + r * 64 + ((g ^ ((r >> 1) & 3)) << 4));
    }

    // staging has 2 iterations of slack -- issue after the critical reads
    if (t + 2 < nt) STAGEB(t + 2);  // overwrites buf (t-1)%3 -- safe post-barrier

#pragma unroll
    for (int mi = 0; mi < 4; ++mi)
#pragma unroll
      for (int ni = 0; ni < 4; ++ni)
        acc[mi][ni] = __builtin_amdgcn_mfma_f32_16x16x32_bf16(aR[mi], bR[ni], acc[mi][ni], 0, 0, 0);
  }
#undef STAGEB

#pragma unroll
  for (int ni = 0; ni < 4; ++ni) {
    long n = bcol + wc * 64 + ni * 16 + lm;
    float bv = bias ? bias[n] : 0.f;
#pragma unroll
    for (int mi = 0; mi < 4; ++mi) {
      long m0 = brow + wr * 64 + mi * 16 + g * 4;
      if (Cvt) {  // V-proj: write vT [b][n][s]
        long b = m0 >> 10, s0 = m0 & 1023;
        alignas(8) bf16 t4[4];
#pragma unroll
        for (int r = 0; r < 4; ++r) t4[r] = __float2bfloat16(acc[mi][ni][r] + bv);
        *reinterpret_cast<ushort4*>(Cvt + ((b << 10) + n) * 1024 + s0) =
            *reinterpret_cast<const ushort4*>(t4);
      } else {
#pragma unroll
        for (int r = 0; r < 4; ++r)
          Cb[(m0 + r) * 1024 + n] = __float2bfloat16(acc[mi][ni][r] + bv);
      }
    }
  }
}

// QKV fused, balanced: K 128 blocks (nt=128), V 128 (nt=128), Q 256 (nt=32).
__global__ __launch_bounds__(512, 4) void gemm_qkv_bal(
    const bf16* __restrict__ Ak, const bf16* __restrict__ Bk, const float* __restrict__ bk_, bf16* __restrict__ Ck, int Kk, int nbk,
    const bf16* __restrict__ Av, const bf16* __restrict__ Bv_, const float* __restrict__ bv_, bf16* __restrict__ CvT, int Kv, int nbv,
    const bf16* __restrict__ Aq, const bf16* __restrict__ Bq_, const float* __restrict__ bq_, bf16* __restrict__ Cq, int Kq) {
  __shared__ bf16 lds[36864];  // 72 KB
  int bid = blockIdx.x;
  const bf16 *A, *Bt; const float* bias; bf16 *C = nullptr, *Cvt = nullptr; int K, l, nb;
  if (bid < nbk)            { A = Ak; Bt = Bk;  bias = bk_; C = Ck;    K = Kk; l = bid;             nb = nbk; }
  else if (bid < nbk + nbv) { A = Av; Bt = Bv_; bias = bv_; Cvt = CvT; K = Kv; l = bid - nbk;       nb = nbv; }
  else                      { A = Aq; Bt = Bq_; bias = bq_; C = Cq;   K = Kq; l = bid - nbk - nbv; nb = gridDim.x - nbk - nbv; }
  int g = (l & 7) * (nb >> 3) + (l >> 3);
  gemm_bal_core(A, Bt, bias, C, Cvt, K, g & 7, g >> 3, lds);
}

// ---------------- 128^2 GEMM (2-buffer, single-barrier) for O-proj ----------
__device__ __forceinline__ void gemm_core(const bf16* __restrict__ A, const bf16* __restrict__ Bt,
                                          const float* __restrict__ bias,
                                          bf16* __restrict__ Cb, float* __restrict__ Cf,
                                          int N, int K, int bx, int by,
                                          bf16* As, bf16* Bs) {
  const int tid = threadIdx.x;
  const int lane = tid & 63, g = lane >> 4, lm = lane & 15;
  const int wid = tid >> 6, wr = wid >> 1, wc = wid & 1;
  const long brow = (long)by * 128, bcol = (long)bx * 128;

  const bf16* asrc[4];
  const bf16* bsrc[4];
  int dsto[4];
#pragma unroll
  for (int t = 0; t < 4; ++t) {
    int sl = tid + t * 256;
    int row = sl >> 3;
    int kg = (sl & 7) ^ (row & 7);
    asrc[t] = A + (brow + row) * (long)K + kg * 8;
    bsrc[t] = Bt + (bcol + row) * (long)K + kg * 8;
    dsto[t] = sl * 16;
  }

  f32x4 zero = {0.f, 0.f, 0.f, 0.f};
  f32x4 acc[4][4];
#pragma unroll
  for (int i = 0; i < 4; ++i)
#pragma unroll
    for (int j = 0; j < 4; ++j) acc[i][j] = zero;

  char* Asc = (char*)As;
  char* Bsc = (char*)Bs;

  // prologue: stage tile 0 into buffer 0
#pragma unroll
  for (int t = 0; t < 4; ++t) {
    gload16(asrc[t], Asc + dsto[t]);
    gload16(bsrc[t], Bsc + dsto[t]);
    asrc[t] += 64; bsrc[t] += 64;
  }

  const int nt = K >> 6;
  for (int i = 0; i < nt; ++i) {
    wait_vm0();      // certify tile i (staged one iter ago)
    barrier_raw();   // resident block-wide; reads of buf(i-1) retired

    const char* Ab = Asc + (i & 1) * 16384;
    const char* Bb = Bsc + (i & 1) * 16384;
    // critical-path ds_reads first
    short8 af[2][4], bfv[2][4];
#pragma unroll
    for (int ks = 0; ks < 2; ++ks) {
#pragma unroll
      for (int mi = 0; mi < 4; ++mi) {
        int m = wr * 64 + mi * 16 + lm;
        af[ks][mi] = *reinterpret_cast<const short8*>(
            Ab + ((m * 128 + ks * 64 + g * 16) ^ ((m & 7) << 4)));
      }
#pragma unroll
      for (int ni = 0; ni < 4; ++ni) {
        int n = wc * 64 + ni * 16 + lm;
        bfv[ks][ni] = *reinterpret_cast<const short8*>(
            Bb + ((n * 128 + ks * 64 + g * 16) ^ ((n & 7) << 4)));
      }
    }

    if (i + 1 < nt) {
      const int nxt = (i + 1) & 1;
#pragma unroll
      for (int t = 0; t < 4; ++t) {
        gload16(asrc[t], Asc + nxt * 16384 + dsto[t]);
        gload16(bsrc[t], Bsc + nxt * 16384 + dsto[t]);
        asrc[t] += 64; bsrc[t] += 64;
      }
    }

#pragma unroll
    for (int ks = 0; ks < 2; ++ks)
#pragma unroll
      for (int mi = 0; mi < 4; ++mi)
#pragma unroll
        for (int ni = 0; ni < 4; ++ni)
          acc[mi][ni] = __builtin_amdgcn_mfma_f32_16x16x32_bf16(af[ks][mi], bfv[ks][ni], acc[mi][ni], 0, 0, 0);
  }

#pragma unroll
  for (int ni = 0; ni < 4; ++ni) {
    long n = bcol + wc * 64 + ni * 16 + lm;
    float bv = bias ? bias[n] : 0.f;
#pragma unroll
    for (int mi = 0; mi < 4; ++mi) {
      long m0 = brow + wr * 64 + mi * 16 + g * 4;
#pragma unroll
      for (int r = 0; r < 4; ++r) {
        float o = acc[mi][ni][r] + bv;
        if (Cb) Cb[(m0 + r) * N + n] = __float2bfloat16(o);
        else    Cf[(m0 + r) * N + n] = o;
      }
    }
  }
}

__global__ __launch_bounds__(256) void gemm_bt(const bf16* __restrict__ A,
                                               const bf16* __restrict__ Bt,
                                               const float* __restrict__ bias,
                                               bf16* __restrict__ Cb,
                                               float* __restrict__ Cf,
                                               int N, int K) {
  __shared__ bf16 As[2 * 128 * 64];
  __shared__ bf16 Bs[2 * 128 * 64];
  int bid = blockIdx.x;
  int g = (bid & 7) * (gridDim.x >> 3) + (bid >> 3);
  gemm_core(A, Bt, bias, Cb, Cf, N, K, g & 7, g >> 3, As, Bs);
}

// ---------------- fused flash attention: 128 q-rows/block, 8 waves ----------
// (R15's version, unchanged: setprio kept here -- helps attn per m191.)
__global__ __launch_bounds__(512) void attn_fused(const bf16* __restrict__ q,
                                                  const bf16* __restrict__ k,
                                                  const bf16* __restrict__ vT,
                                                  bf16* __restrict__ o) {
  constexpr float C2 = 0.18033688011112042f;  // (1/8) * log2(e)
  constexpr float THR = 6.0f;
  __shared__ bf16 Kl[2][64 * 64];   // 16 KB
  __shared__ bf16 Vl[2][64 * 64];   // 16 KB
  __shared__ bf16 Pl[8][16 * 64];   // 16 KB
  const int tid = threadIdx.x;
  const int lane = tid & 63, g = lane >> 4, lm = lane & 15;
  const int wid = tid >> 6;
  int bid = blockIdx.x;
  int gl = (bid & 7) * 128 + (bid >> 3);
  const int qt = gl & 15, bh = gl >> 4;
  const int b = bh >> 4, h = bh & 15;
  const int qbase = qt * 128 + wid * 16;

  const bf16* qrow = q + (long)(b * Lc + qbase + lm) * DModel + h * 64;
  short8 qa0 = *reinterpret_cast<const short8*>(qrow + g * 8);
  short8 qa1 = *reinterpret_cast<const short8*>(qrow + 32 + g * 8);
#pragma unroll
  for (int j = 0; j < 8; ++j) {
    union { ushort u; bf16 h; } cv;
    cv.u = (ushort)qa0[j];
    bf16 s0 = __float2bfloat16(__bfloat162float(cv.h) * C2);
    qa0[j] = (short)*reinterpret_cast<ushort*>(&s0);
    cv.u = (ushort)qa1[j];
    bf16 s1 = __float2bfloat16(__bfloat162float(cv.h) * C2);
    qa1[j] = (short)*reinterpret_cast<ushort*>(&s1);
  }

  const bf16* kbase = k + (long)b * Sc * DModel + h * 64;
  const bf16* vbase = vT + ((long)b * DModel + h * 64) * Sc;

  const int srow = tid >> 3;
  const int scg = (tid & 7) ^ (srow & 7);
  const bf16* ksrc = kbase + (long)srow * DModel + scg * 8;
  const bf16* vsrc = vbase + (long)srow * Sc + scg * 8;
  const int dsto = tid * 16;

  f32x4 zero = {0.f, 0.f, 0.f, 0.f};
  f32x4 accO[4];
#pragma unroll
  for (int i = 0; i < 4; ++i) accO[i] = zero;
  f32x4 accL = zero;
  float mst[4] = {-1e30f, -1e30f, -1e30f, -1e30f};

  short8 vones;
#pragma unroll
  for (int j = 0; j < 8; ++j) vones[j] = (short)0x3F80;

  char* Klc = (char*)Kl;
  char* Vlc = (char*)Vl;
  char* Plc = (char*)Pl + wid * (16 * 64 * 2);

  gload16(ksrc, Klc + dsto);
  gload16(vsrc, Vlc + dsto);
  ksrc += 64 * DModel; vsrc += 64;

  for (int j = 0; j < Sc / 64; ++j) {
    const int cur = j & 1;
    wait_vm0();      // certify tile j (staged one iter ago)
    barrier_raw();   // resident; reads of buf(j-1) retired
    if (j + 1 < Sc / 64) {
      const int nxt = cur ^ 1;
      gload16(ksrc, Klc + nxt * 8192 + dsto);
      gload16(vsrc, Vlc + nxt * 8192 + dsto);
      ksrc += 64 * DModel; vsrc += 64;
    }

    const char* Kb = Klc + cur * 8192;
    const char* Vb = Vlc + cur * 8192;

    f32x4 scv[4];
    __builtin_amdgcn_s_setprio(1);
#pragma unroll
    for (int st = 0; st < 4; ++st) {
      int s = st * 16 + lm;
      int sw = (s & 7) << 4;
      short8 kb0 = *reinterpret_cast<const short8*>(Kb + ((s * 128 + g * 16) ^ sw));
      short8 kb1 = *reinterpret_cast<const short8*>(Kb + ((s * 128 + 64 + g * 16) ^ sw));
      f32x4 z = zero;
      z = __builtin_amdgcn_mfma_f32_16x16x32_bf16(qa0, kb0, z, 0, 0, 0);
      z = __builtin_amdgcn_mfma_f32_16x16x32_bf16(qa1, kb1, z, 0, 0, 0);
      scv[st] = z;
    }
    __builtin_amdgcn_s_setprio(0);

    float pmax[4];
#pragma unroll
    for (int r = 0; r < 4; ++r)
      pmax[r] = fmaxf(fmaxf(scv[0][r], scv[1][r]), fmaxf(scv[2][r], scv[3][r]));
    int need = 0;
#pragma unroll
    for (int r = 0; r < 4; ++r) need |= (pmax[r] > mst[r] + THR) ? 1 : 0;
    if (__any(need)) {
#pragma unroll
      for (int r = 0; r < 4; ++r) {
        float mx = pmax[r];
        mx = fmaxf(mx, __shfl_xor(mx, 1));
        mx = fmaxf(mx, __shfl_xor(mx, 2));
        mx = fmaxf(mx, __shfl_xor(mx, 4));
        mx = fmaxf(mx, __shfl_xor(mx, 8));
        float mnew = fmaxf(mst[r], mx);
        float corr = __builtin_amdgcn_exp2f(mst[r] - mnew);
        mst[r] = mnew;
        accL[r] *= corr;
#pragma unroll
        for (int et = 0; et < 4; ++et) accO[et][r] *= corr;
      }
    }
#pragma unroll
    for (int r = 0; r < 4; ++r) {
      int qq = g * 4 + r;
      int swp = (qq & 7) << 4;
#pragma unroll
      for (int st = 0; st < 4; ++st) {
        float p = __builtin_amdgcn_exp2f(scv[st][r] - mst[r]);
        *reinterpret_cast<bf16*>(Plc + ((qq * 128 + (st * 16 + lm) * 2) ^ swp)) =
            __float2bfloat16(p);
      }
    }

    __builtin_amdgcn_s_setprio(1);
#pragma unroll
    for (int sk = 0; sk < 2; ++sk) {
      short8 pa = *reinterpret_cast<const short8*>(
          Plc + ((lm * 128 + sk * 64 + g * 16) ^ ((lm & 7) << 4)));
      accL = __builtin_amdgcn_mfma_f32_16x16x32_bf16(pa, vones, accL, 0, 0, 0);
#pragma unroll
      for (int et = 0; et < 4; ++et) {
        int e = et * 16 + lm;
        short8 vb = *reinterpret_cast<const short8*>(
            Vb + ((e * 128 + sk * 64 + g * 16) ^ ((e & 7) << 4)));
        accO[et] = __builtin_amdgcn_mfma_f32_16x16x32_bf16(pa, vb, accO[et], 0, 0, 0);
      }
    }
    __builtin_amdgcn_s_setprio(0);
  }

#pragma unroll
  for (int r = 0; r < 4; ++r) {
    float inv = 1.0f / accL[r];
    long row = (long)(b * Lc + qbase + g * 4 + r);
#pragma unroll
    for (int et = 0; et < 4; ++et)
      o[row * DModel + h * 64 + et * 16 + lm] = __float2bfloat16(accO[et][r] * inv);
  }
}

// ---------------- host launch ----------------
extern "C" void kernel_launch(void* const* d_in, const int* in_sizes, int n_in,
                              void* d_out, int out_size, void* d_ws, size_t ws_size,
                              hipStream_t stream) {
  const float* tgt = (const float*)d_in[0];
  const float* src = (const float*)d_in[1];
  const float* val = (const float*)d_in[2];
  const float* Wq  = (const float*)d_in[3];
  const float* bq  = (const float*)d_in[4];
  const float* Wk  = (const float*)d_in[5];
  const float* bk  = (const float*)d_in[6];
  const float* Wv  = (const float*)d_in[7];
  const float* bv  = (const float*)d_in[8];
  const float* Wo  = (const float*)d_in[9];
  const float* bo  = (const float*)d_in[10];
  float* out = (float*)d_out;
  char* ws = (char*)d_ws;

  const long n4_tgt = (long)8192 * 1024 / 4;
  const long n4_sv  = (long)4096 * 4096 / 4;

  if (ws_size < (132ul << 20)) return;

  bf16* WqT  = (bf16*)(ws + (0l   << 20));  // 2 MB
  bf16* WkT  = (bf16*)(ws + (2l   << 20));  // 8 MB
  bf16* WvT  = (bf16*)(ws + (10l  << 20));  // 8 MB
  bf16* WoT  = (bf16*)(ws + (18l  << 20));  // 2 MB
  bf16* tgtb = (bf16*)(ws + (20l  << 20));  // 16 MB (attn out aliases later)
  bf16* srcb = (bf16*)(ws + (36l  << 20));  // 32 MB
  bf16* valb = (bf16*)(ws + (68l  << 20));  // 32 MB
  bf16* qb   = (bf16*)(ws + (100l << 20));  // 16 MB
  bf16* kb   = (bf16*)(ws + (116l << 20));  // 8 MB
  bf16* vTb  = (bf16*)(ws + (124l << 20));  // 8 MB [4][1024][1024] -> 132 MB
  bf16* attnb = tgtb;  // tgtb dead after QKV gemm

  prep<<<10240 + 4096, 256, 0, stream>>>(Wq, WqT, Wk, WkT, Wv, WvT, Wo, WoT,
                                         tgt, tgtb, n4_tgt, src, srcb, n4_sv,
                                         val, valb, n4_sv);
  gemm_qkv_bal<<<512, 512, 0, stream>>>(srcb, WkT, bk, kb, 4096, 128,
                                        valb, WvT, bv, vTb, 4096, 128,
                                        tgtb, WqT, bq, qb, 1024);
  attn_fused<<<1024, 512, 0, stream>>>(qb, kb, vTb, attnb);
  gemm_bt<<<512, 256, 0, stream>>>(attnb, WoT, bo, (bf16*)nullptr, out, 1024, 1024);
}